// Round 1
// baseline (354.619 us; speedup 1.0000x reference)
//
#include <hip/hip_runtime.h>

#define LVAL 256
#define T    32
#define ST   36          // slab row stride (floats): 144 B, 16B-aligned
#define SLAB (T * ST)
#define NB   8
#define NEG  (-1e30f)

// wave-synchronous LDS step fence: drain DS ops + block compiler reordering
#define LDS_FENCE() asm volatile("s_waitcnt lgkmcnt(0)" ::: "memory")

__device__ __forceinline__ size_t sidx(int b, int i, int e) {
    return ((size_t)b << 16) + (i << 8) + e;
}

// VALU cross-lane max via DPP quad_perm (no LDS/swizzle latency)
template<int CTRL>
__device__ __forceinline__ float dpp_max(float v) {
#if __has_builtin(__builtin_amdgcn_mov_dpp)
    int o = __builtin_amdgcn_mov_dpp(__builtin_bit_cast(int, v), CTRL, 0xF, 0xF, true);
    return fmaxf(v, __builtin_bit_cast(float, o));
#else
    return fmaxf(v, __shfl_xor(v, CTRL == 0xB1 ? 1 : 2));
#endif
}

// Phase 1: t[b,i,e] = max_c scores[b,i,e,c] -> f32 s[b][i][e], strict upper only.
// Also re-initializes the persistent-kernel barrier state each launch.
__global__ __launch_bounds__(256) void phase1(const float* __restrict__ scores,
                                              float* __restrict__ s,
                                              int* __restrict__ bar) {
    if (blockIdx.x == 0 && blockIdx.y == 0) {
        for (int k = threadIdx.x; k < 2048; k += 256) bar[k] = 0;
    }
    const int i = blockIdx.x, b = blockIdx.y;
    const int sub = threadIdx.x & 15, slot = threadIdx.x >> 4;
    const float* row = scores + ((((size_t)b * LVAL + i) * LVAL) << 6);
    #pragma unroll 4
    for (int m0 = 0; m0 < LVAL; m0 += 16) {
        const int e = m0 + slot;
        if (e > i) {
            float4 v = *((const float4*)(row + ((size_t)e << 6)) + sub);
            float mx = fmaxf(fmaxf(v.x, v.y), fmaxf(v.z, v.w));
            #pragma unroll
            for (int d = 1; d < 16; d <<= 1) mx = fmaxf(mx, __shfl_xor(mx, d));
            if (sub == 0) s[sidx(b, i, e)] = mx;
        }
    }
}

// One wave-synchronous DP step inside a diagonal block (round 0).
template<int LP>
__device__ __forceinline__ void diag_step(int lane, int l,
                                          float (*cur)[ST], float (*curT)[ST],
                                          const float (*tb)[ST]) {
    const int cells = T - l;
    const int P = 1 << LP;
    const int c = lane >> LP, p = lane & (P - 1);
    const bool guard = c < cells;
    const int li = guard ? c : 0;
    const int le = guard ? c + l : 0;
    constexpr int NF = 8 >> LP;
    const float tv = tb[li][le];
    float acc = NEG;
    #pragma unroll
    for (int m = 0; m < NF; ++m) {
        const int k0 = 4 * (p + m * P);
        float4 cu = *(const float4*)&cur[li][k0];
        float4 ct = *(const float4*)&curT[le][k0];
        acc = fmaxf(acc, fmaxf(fmaxf(cu.x + ct.x, cu.y + ct.y),
                               fmaxf(cu.z + ct.z, cu.w + ct.w)));
    }
    acc = dpp_max<0xB1>(acc);                 // xor 1
    if (LP >= 2) acc = dpp_max<0x4E>(acc);    // xor 2
    const float v = acc + tv;
    if (guard && p == 0) cur[li][le] = v;
    if (guard && p == 1) curT[le][li] = v;
}

// One wave-synchronous edge step of round D. All splits scanned maskless:
// Ae/BeT pre-masked with NEG, cur/curT hold NEG in not-yet-final slots.
template<int LP>
__device__ __forceinline__ void edge_step(int lane, int l, int D,
                                          const float (*Ae)[ST], const float (*BeT)[ST],
                                          float (*cur)[ST], float (*curT)[ST],
                                          const float (*tb)[ST], const float (*pre)[ST]) {
    const int delta = l - (T - 1);
    const int ad = delta < 0 ? -delta : delta;
    const int cells = T - ad;
    const int P = 1 << LP;
    const int c = lane >> LP, p = lane & (P - 1);
    const bool guard = c < cells;
    const int li = guard ? (delta < 0 ? c + ad : c) : 0;
    const int le = guard ? li + delta : 0;
    constexpr int NF = 8 >> LP;
    const float tv = tb[li][le];
    float acc = pre[li][le];                   // middle-K GEMM partial (NEG if none)
    #pragma unroll
    for (int m = 0; m < NF; ++m) {
        const int k0 = 4 * (p + m * P);
        float4 a  = *(const float4*)&Ae[li][k0];     // split in left edge block
        float4 ct = *(const float4*)&curT[le][k0];
        float4 cu = *(const float4*)&cur[li][k0];    // split in right edge block
        float4 bt = *(const float4*)&BeT[le][k0];
        float s0 = fmaxf(fmaxf(a.x + ct.x, a.y + ct.y), fmaxf(a.z + ct.z, a.w + ct.w));
        float s1 = fmaxf(fmaxf(cu.x + bt.x, cu.y + bt.y), fmaxf(cu.z + bt.z, cu.w + bt.w));
        acc = fmaxf(acc, fmaxf(s0, s1));
    }
    acc = dpp_max<0xB1>(acc);
    if (LP >= 2) acc = dpp_max<0x4E>(acc);
    const float v = (D == 1 && l == 0) ? tv : acc + tv;   // w==1 cell: value is t
    if (guard && p == 0) cur[li][le] = v;
    if (guard && p == 1) curT[le][li] = v;
}

// Per-batch (8-block) sense barrier. Agent-scope release/acquire so cross-XCD
// placement is still correct; spin bails out after ~0.5 Gcycle so a logic bug
// fails the checker loudly instead of hanging the harness.
__device__ __forceinline__ void batch_barrier(int* __restrict__ bar, int b,
                                              int tid, int ep) {
    __syncthreads();
    if (tid == 0) {
        int* cnt  = bar + b * 256;
        int* flag = bar + b * 256 + 64;
        __threadfence();                       // release: flush our stores (wbL2)
        int prev = __hip_atomic_fetch_add(cnt, 1, __ATOMIC_ACQ_REL,
                                          __HIP_MEMORY_SCOPE_AGENT);
        if (prev == NB - 1) {
            __hip_atomic_store(cnt, 0, __ATOMIC_RELAXED, __HIP_MEMORY_SCOPE_AGENT);
            __hip_atomic_store(flag, ep, __ATOMIC_RELEASE, __HIP_MEMORY_SCOPE_AGENT);
        } else {
            int guard = 0;
            while (__hip_atomic_load(flag, __ATOMIC_RELAXED,
                                     __HIP_MEMORY_SCOPE_AGENT) < ep) {
                __builtin_amdgcn_s_sleep(2);
                if (++guard > (1 << 22)) break;
            }
        }
        __threadfence();                       // acquire: invalidate stale caches
    }
    __syncthreads();
}

// Fused DP: block (b, bi) owns block-row bi of batch b and computes (bi, bi+D)
// for D = 0..7-bi. Its own outputs stay resident in LDS (transposed) as the
// GEMM A-operands for all later rounds; only B-columns/diagonals cross blocks
// (through global s, ordered by the per-batch barrier).
__global__ __launch_bounds__(256) void dp_fused(float* __restrict__ s,
                                                const int* __restrict__ lens,
                                                float* __restrict__ out,
                                                int* __restrict__ bar) {
    __shared__ __align__(16) float smem[14 * SLAB];      // 64512 B
    float* ATb = smem;                                   // 6 persistent A^T slabs
    float (*Ae)[ST]  = (float(*)[ST])(smem + 6 * SLAB);  // own diag, masked (round0 out)
    float (*tb)[ST]  = (float(*)[ST])(smem + 7 * SLAB);  // t block (bi,be), prefetched
    float (*BeT)[ST] = (float(*)[ST])(smem + 8 * SLAB);  // diag be, masked, prefetched
    float (*cur)[ST] = (float(*)[ST])(smem + 9 * SLAB);
    float* BWb = smem + 10 * SLAB;                       // 4 per-wave GEMM slabs
    float (*pre)[ST] = (float(*)[ST])BWb;                // = BW0 (after combine)

    const int b  = blockIdx.x & 7;                       // batch -> same XCD group
    const int bi = blockIdx.x >> 3;
    const int tid = threadIdx.x, wid = tid >> 6, lane = tid & 63;
    const int lr = tid >> 5, lc = tid & 31;
    const int grow = lane >> 1, gc = (lane & 1) * 16;
    const int gly = lane >> 3, glx = lane & 7, r0 = 4 * gly, c0 = 4 * glx;
    const int trow = tid >> 3, tc4 = (tid & 7) * 4;
    float (*BW)[ST] = (float(*)[ST])(BWb + wid * SLAB);

    // ---- round 0: wave0 runs the diag DP into Ae; waves 1-3 prefetch tb(D=1)
    if (wid == 0) {
        float (*curT0)[ST] = (float(*)[ST])(BWb + 1 * SLAB);
        float (*t0)[ST]    = (float(*)[ST])(BWb + 2 * SLAB);
        const float4 negv = make_float4(NEG, NEG, NEG, NEG);
        #pragma unroll
        for (int j = 0; j < 4; ++j) {
            float4 v = *(const float4*)&s[sidx(b, bi * T + grow, bi * T + gc + 4 * j)];
            *(float4*)&t0[grow][gc + 4 * j]    = v;
            *(float4*)&Ae[grow][gc + 4 * j]    = negv;
            *(float4*)&curT0[grow][gc + 4 * j] = negv;
        }
        LDS_FENCE();
        if (lane < T - 1) {                    // w == 1 diagonal = t (final)
            float v = t0[lane][lane + 1];
            Ae[lane][lane + 1] = v;
            curT0[lane + 1][lane] = v;
        }
        LDS_FENCE();
        #pragma unroll 1
        for (int l = 2; l < T; ++l) {
            if (T - l <= 16) diag_step<2>(lane, l, Ae, curT0, t0);
            else             diag_step<1>(lane, l, Ae, curT0, t0);
            LDS_FENCE();
        }
        #pragma unroll
        for (int j = 0; j < 4; ++j)            // publish diag (NEG lower kept)
            *(float4*)&s[sidx(b, bi * T + grow, bi * T + gc + 4 * j)] =
                *(const float4*)&Ae[grow][gc + 4 * j];
    } else if (bi + 1 < NB) {
        for (int idx = tid - 64; idx < 256; idx += 192) {
            const int row = idx >> 3, c4 = (idx & 7) * 4;
            *(float4*)&tb[row][c4] =
                *(const float4*)&s[sidx(b, bi * T + row, (bi + 1) * T + c4)];
        }
    }

    // ---- rounds 1..7 ----
    #pragma unroll 1
    for (int D = 1; D < NB; ++D) {
        batch_barrier(bar, b, tid, D);
        const int be = bi + D;
        if (be < NB) {
            if (D == 1) {                      // diag be only final after barrier 1
                float4 v = *(const float4*)&s[sidx(b, be * T + trow, be * T + tc4)];
                BeT[tc4 + 0][trow] = (trow < tc4 + 0) ? v.x : NEG;
                BeT[tc4 + 1][trow] = (trow < tc4 + 1) ? v.y : NEG;
                BeT[tc4 + 2][trow] = (trow < tc4 + 2) ? v.z : NEG;
                BeT[tc4 + 3][trow] = (trow < tc4 + 3) ? v.w : NEG;
            }
            // GEMM over middle K blocks: A^T resident in LDS, B staged per wave
            const int nw = (D - 1 < 4) ? (D - 1) : 4;
            float ag[4][4];
            #pragma unroll
            for (int i = 0; i < 4; ++i)
                #pragma unroll
                for (int j = 0; j < 4; ++j) ag[i][j] = NEG;
            for (int K = bi + 1 + wid; K < be; K += 4) {
                const float (*AT)[ST] = (const float(*)[ST])(ATb + (K - bi - 1) * SLAB);
                #pragma unroll
                for (int j = 0; j < 4; ++j) {
                    float4 bv = *(const float4*)&s[sidx(b, K * T + grow, be * T + gc + 4 * j)];
                    *(float4*)&BW[grow][gc + 4 * j] = bv;
                }
                LDS_FENCE();                   // wave-private BW slab
                #pragma unroll 4
                for (int k = 0; k < T; ++k) {
                    float4 a4 = *(const float4*)&AT[k][r0];
                    float4 b4 = *(const float4*)&BW[k][c0];
                    const float aa[4] = {a4.x, a4.y, a4.z, a4.w};
                    const float bb[4] = {b4.x, b4.y, b4.z, b4.w};
                    #pragma unroll
                    for (int i = 0; i < 4; ++i)
                        #pragma unroll
                        for (int j = 0; j < 4; ++j)
                            ag[i][j] = fmaxf(ag[i][j], aa[i] + bb[j]);
                }
                LDS_FENCE();
            }
            if (wid < nw) {
                #pragma unroll
                for (int i = 0; i < 4; ++i)
                    *(float4*)&BW[r0 + i][c0] =
                        make_float4(ag[i][0], ag[i][1], ag[i][2], ag[i][3]);
            }
            __syncthreads();
            #pragma unroll
            for (int r = 0; r < 4; ++r) {      // combine wave partials -> pre (=BW0)
                const int row = lr + 8 * r;
                float v = NEG;
                for (int w2 = 0; w2 < nw; ++w2)
                    v = fmaxf(v, BWb[w2 * SLAB + row * ST + lc]);
                pre[row][lc] = v;
            }
            __syncthreads();
            // curT target: persistent A^T slab for D<7 (future GEMM A), scratch last
            float (*curT)[ST] = (D == NB - 1) ? (float(*)[ST])(BWb + 1 * SLAB)
                                              : (float(*)[ST])(ATb + (D - 1) * SLAB);
            #pragma unroll
            for (int r = 0; r < 4; ++r) {
                const int row = lr + 8 * r;
                cur[row][lc]  = NEG;
                curT[row][lc] = NEG;
            }
            __syncthreads();
            if (wid == 0) {                    // barrier-free edge pass
                #pragma unroll 1
                for (int l = 0; l < 2 * T - 1; ++l) {
                    const int ad0 = (l < T - 1) ? (T - 1 - l) : (l - (T - 1));
                    if (ad0 >= 16) edge_step<2>(lane, l, D, Ae, BeT, cur, curT, tb, pre);
                    else           edge_step<1>(lane, l, D, Ae, BeT, cur, curT, tb, pre);
                    LDS_FENCE();
                }
            }
            __syncthreads();
            #pragma unroll
            for (int r = 0; r < 4; ++r)        // publish (bi,be) for other rows
                s[sidx(b, bi * T + lr + 8 * r, be * T + lc)] = cur[lr + 8 * r][lc];
            if (be + 1 < NB) {                 // prefetch next round's tb/BeT
                *(float4*)&tb[trow][tc4] =
                    *(const float4*)&s[sidx(b, bi * T + trow, (be + 1) * T + tc4)];
                float4 v = *(const float4*)&s[sidx(b, (be + 1) * T + trow,
                                                   (be + 1) * T + tc4)];
                BeT[tc4 + 0][trow] = (trow < tc4 + 0) ? v.x : NEG;
                BeT[tc4 + 1][trow] = (trow < tc4 + 1) ? v.y : NEG;
                BeT[tc4 + 2][trow] = (trow < tc4 + 2) ? v.z : NEG;
                BeT[tc4 + 3][trow] = (trow < tc4 + 3) ? v.w : NEG;
            }
        }
    }

    // Fused finalize: block (b,0) owns row 0, everything needed is in its LDS.
    if (bi == 0 && tid == 0) {
        int len = lens[b];
        len = len < 1 ? 1 : (len > LVAL - 1 ? LVAL - 1 : len);
        const int K = len >> 5, off = len & 31;
        float r;
        if (K == 0)           r = Ae[0][off];
        else if (K == NB - 1) r = cur[0][off];
        else                  r = ATb[(K - 1) * SLAB + off * ST];
        out[b] = r;
    }
}

extern "C" void kernel_launch(void* const* d_in, const int* in_sizes, int n_in,
                              void* d_out, int out_size, void* d_ws, size_t ws_size,
                              hipStream_t stream) {
    const float* scores = (const float*)d_in[0];
    const int*   lens   = (const int*)d_in[1];
    float*       out    = (float*)d_out;
    float*       s      = (float*)d_ws;               // 8 * 256 * 256 f32 = 2 MB
    int*         bar    = (int*)((char*)d_ws + ((size_t)(8) << 16) * sizeof(float));

    phase1<<<dim3(LVAL, 8), 256, 0, stream>>>(scores, s, bar);
    dp_fused<<<64, 256, 0, stream>>>(s, lens, out, bar);
}

// Round 2
// 339.048 us; speedup vs baseline: 1.0459x; 1.0459x over previous
//
#include <hip/hip_runtime.h>

#define LVAL 256
#define T    32
#define ST   36          // slab row stride (floats): 144 B, 16B-aligned
#define SLAB (T * ST)
#define NB   8
#define NEG  (-1e30f)

typedef float f32x4 __attribute__((ext_vector_type(4)));

// Compiler-only reorder fence. HW: DS ops of one wave are processed in order
// by the DS pipe, so cross-lane LDS RAW within a single wave needs no
// lgkmcnt(0) drain; we only stop the compiler from reordering/caching.
#define SOFT_FENCE() asm volatile("" ::: "memory")

__device__ __forceinline__ size_t sidx(int b, int i, int e) {
    return ((size_t)b << 16) + (i << 8) + e;
}

// ---- coherent (MALL-level) accesses for cross-block data: bypass L1/L2 ----
__device__ __forceinline__ void st_coh4(float* p, f32x4 v) {
    asm volatile("global_store_dwordx4 %0, %1, off sc0 sc1"
                 :: "v"(p), "v"(v) : "memory");
}
__device__ __forceinline__ f32x4 ld_coh4(const float* p) {
    f32x4 v;
    asm volatile("global_load_dwordx4 %0, %1, off sc0 sc1\n\t"
                 "s_waitcnt vmcnt(0)"
                 : "=&v"(v) : "v"(p) : "memory");
    return v;
}
__device__ __forceinline__ void ld_coh4x4(const float* p,
                                          f32x4& a, f32x4& b, f32x4& c, f32x4& d) {
    asm volatile("global_load_dwordx4 %0, %4, off sc0 sc1\n\t"
                 "global_load_dwordx4 %1, %4, off offset:16 sc0 sc1\n\t"
                 "global_load_dwordx4 %2, %4, off offset:32 sc0 sc1\n\t"
                 "global_load_dwordx4 %3, %4, off offset:48 sc0 sc1\n\t"
                 "s_waitcnt vmcnt(0)"
                 : "=&v"(a), "=&v"(b), "=&v"(c), "=&v"(d)
                 : "v"(p) : "memory");
}

// VALU cross-lane max via DPP quad_perm (no LDS/swizzle latency)
template<int CTRL>
__device__ __forceinline__ float dpp_max(float v) {
#if __has_builtin(__builtin_amdgcn_mov_dpp)
    int o = __builtin_amdgcn_mov_dpp(__builtin_bit_cast(int, v), CTRL, 0xF, 0xF, true);
    return fmaxf(v, __builtin_bit_cast(float, o));
#else
    return fmaxf(v, __shfl_xor(v, CTRL == 0xB1 ? 1 : 2));
#endif
}

// Phase 1: t[b,i,e] = max_c scores[b,i,e,c] -> f32 s[b][i][e], strict upper only.
// Also re-initializes the persistent-kernel barrier state each launch.
__global__ __launch_bounds__(256) void phase1(const float* __restrict__ scores,
                                              float* __restrict__ s,
                                              int* __restrict__ bar) {
    if (blockIdx.x == 0 && blockIdx.y == 0) {
        for (int k = threadIdx.x; k < 2048; k += 256) bar[k] = 0;
    }
    const int i = blockIdx.x, b = blockIdx.y;
    const int sub = threadIdx.x & 15, slot = threadIdx.x >> 4;
    const float* row = scores + ((((size_t)b * LVAL + i) * LVAL) << 6);
    #pragma unroll 4
    for (int m0 = 0; m0 < LVAL; m0 += 16) {
        const int e = m0 + slot;
        if (e > i) {
            float4 v = *((const float4*)(row + ((size_t)e << 6)) + sub);
            float mx = fmaxf(fmaxf(v.x, v.y), fmaxf(v.z, v.w));
            #pragma unroll
            for (int d = 1; d < 16; d <<= 1) mx = fmaxf(mx, __shfl_xor(mx, d));
            if (sub == 0) s[sidx(b, i, e)] = mx;
        }
    }
}

// One wave-synchronous DP step inside a diagonal block (round 0).
template<int LP>
__device__ __forceinline__ void diag_step(int lane, int l,
                                          float (*cur)[ST], float (*curT)[ST],
                                          const float (*tb)[ST]) {
    const int cells = T - l;
    const int P = 1 << LP;
    const int c = lane >> LP, p = lane & (P - 1);
    const bool guard = c < cells;
    const int li = guard ? c : 0;
    const int le = guard ? c + l : 0;
    constexpr int NF = 8 >> LP;
    const float tv = tb[li][le];
    float acc = NEG;
    #pragma unroll
    for (int m = 0; m < NF; ++m) {
        const int k0 = 4 * (p + m * P);
        float4 cu = *(const float4*)&cur[li][k0];
        float4 ct = *(const float4*)&curT[le][k0];
        acc = fmaxf(acc, fmaxf(fmaxf(cu.x + ct.x, cu.y + ct.y),
                               fmaxf(cu.z + ct.z, cu.w + ct.w)));
    }
    acc = dpp_max<0xB1>(acc);                 // xor 1
    if (LP >= 2) acc = dpp_max<0x4E>(acc);    // xor 2
    const float v = acc + tv;
    if (guard && p == 0) cur[li][le] = v;
    if (guard && p == 1) curT[le][li] = v;
}

// One wave-synchronous edge step of round D. All splits scanned maskless:
// Ae/BeT pre-masked with NEG, cur/curT hold NEG in not-yet-final slots.
template<int LP>
__device__ __forceinline__ void edge_step(int lane, int l, int D,
                                          const float (*Ae)[ST], const float (*BeT)[ST],
                                          float (*cur)[ST], float (*curT)[ST],
                                          const float (*tb)[ST], const float (*pre)[ST]) {
    const int delta = l - (T - 1);
    const int ad = delta < 0 ? -delta : delta;
    const int cells = T - ad;
    const int P = 1 << LP;
    const int c = lane >> LP, p = lane & (P - 1);
    const bool guard = c < cells;
    const int li = guard ? (delta < 0 ? c + ad : c) : 0;
    const int le = guard ? li + delta : 0;
    constexpr int NF = 8 >> LP;
    const float tv = tb[li][le];
    float acc = pre[li][le];                   // middle-K GEMM partial (NEG if none)
    #pragma unroll
    for (int m = 0; m < NF; ++m) {
        const int k0 = 4 * (p + m * P);
        float4 a  = *(const float4*)&Ae[li][k0];     // split in left edge block
        float4 ct = *(const float4*)&curT[le][k0];
        float4 cu = *(const float4*)&cur[li][k0];    // split in right edge block
        float4 bt = *(const float4*)&BeT[le][k0];
        float s0 = fmaxf(fmaxf(a.x + ct.x, a.y + ct.y), fmaxf(a.z + ct.z, a.w + ct.w));
        float s1 = fmaxf(fmaxf(cu.x + bt.x, cu.y + bt.y), fmaxf(cu.z + bt.z, cu.w + bt.w));
        acc = fmaxf(acc, fmaxf(s0, s1));
    }
    acc = dpp_max<0xB1>(acc);
    if (LP >= 2) acc = dpp_max<0x4E>(acc);
    const float v = (D == 1 && l == 0) ? tv : acc + tv;   // w==1 cell: value is t
    if (guard && p == 0) cur[li][le] = v;
    if (guard && p == 1) curT[le][li] = v;
}

// Per-batch (8-block) barrier, fence-free. All cross-block data moves via
// sc0/sc1 coherent accesses (MALL is the common point), so no L2 wb/inv is
// needed: drain own stores (vmcnt), monotonic arrival counter, relaxed spin.
__device__ __forceinline__ void batch_barrier(int* __restrict__ bar, int b,
                                              int tid, int ep) {
    asm volatile("s_waitcnt vmcnt(0)" ::: "memory");   // own coh-stores done
    __syncthreads();
    if (tid == 0) {
        int* cnt  = bar + b * 256;
        int* flag = bar + b * 256 + 64;
        int prev = __hip_atomic_fetch_add(cnt, 1, __ATOMIC_RELAXED,
                                          __HIP_MEMORY_SCOPE_AGENT);
        if ((prev & (NB - 1)) == NB - 1) {             // last arriver of epoch
            __hip_atomic_store(flag, ep, __ATOMIC_RELAXED, __HIP_MEMORY_SCOPE_AGENT);
        } else {
            int guard = 0;
            while (__hip_atomic_load(flag, __ATOMIC_RELAXED,
                                     __HIP_MEMORY_SCOPE_AGENT) < ep) {
                __builtin_amdgcn_s_sleep(2);
                if (++guard > (1 << 22)) break;        // fail loudly, not hang
            }
        }
    }
    __syncthreads();
}

// Fused DP: block (b, bi) owns block-row bi of batch b and computes (bi, bi+D)
// for D = 0..7-bi. Its own outputs stay resident in LDS (transposed) as the
// GEMM A-operands for all later rounds; only B-columns/diagonals cross blocks
// (via sc0/sc1-coherent accesses to global s, ordered by the batch barrier).
__global__ __launch_bounds__(256) void dp_fused(float* __restrict__ s,
                                                const int* __restrict__ lens,
                                                float* __restrict__ out,
                                                int* __restrict__ bar) {
    __shared__ __align__(16) float smem[14 * SLAB];      // 64512 B
    float* ATb = smem;                                   // 6 persistent A^T slabs
    float (*Ae)[ST]  = (float(*)[ST])(smem + 6 * SLAB);  // own diag, masked (round0 out)
    float (*tb)[ST]  = (float(*)[ST])(smem + 7 * SLAB);  // t block (bi,be), prefetched
    float (*BeT)[ST] = (float(*)[ST])(smem + 8 * SLAB);  // diag be, masked, prefetched
    float (*cur)[ST] = (float(*)[ST])(smem + 9 * SLAB);
    float* BWb = smem + 10 * SLAB;                       // 4 per-wave GEMM slabs
    float (*pre)[ST] = (float(*)[ST])BWb;                // = BW0 (after combine)

    const int b  = blockIdx.x & 7;                       // batch -> same XCD group
    const int bi = blockIdx.x >> 3;
    const int tid = threadIdx.x, wid = tid >> 6, lane = tid & 63;
    const int lr = tid >> 5, lc = tid & 31;
    const int grow = lane >> 1, gc = (lane & 1) * 16;
    const int gly = lane >> 3, glx = lane & 7, r0 = 4 * gly, c0 = 4 * glx;
    const int trow = tid >> 3, tc4 = (tid & 7) * 4;
    float (*BW)[ST] = (float(*)[ST])(BWb + wid * SLAB);

    // ---- round 0: wave0 runs the diag DP into Ae; waves 1-3 prefetch tb(D=1)
    if (wid == 0) {
        float (*curT0)[ST] = (float(*)[ST])(BWb + 1 * SLAB);
        float (*t0)[ST]    = (float(*)[ST])(BWb + 2 * SLAB);
        const float4 negv = make_float4(NEG, NEG, NEG, NEG);
        #pragma unroll
        for (int j = 0; j < 4; ++j) {
            float4 v = *(const float4*)&s[sidx(b, bi * T + grow, bi * T + gc + 4 * j)];
            *(float4*)&t0[grow][gc + 4 * j]    = v;
            *(float4*)&Ae[grow][gc + 4 * j]    = negv;
            *(float4*)&curT0[grow][gc + 4 * j] = negv;
        }
        SOFT_FENCE();
        if (lane < T - 1) {                    // w == 1 diagonal = t (final)
            float v = t0[lane][lane + 1];
            Ae[lane][lane + 1] = v;
            curT0[lane + 1][lane] = v;
        }
        SOFT_FENCE();
        #pragma unroll 1
        for (int l = 2; l < T; ++l) {
            if (T - l <= 16) diag_step<2>(lane, l, Ae, curT0, t0);
            else             diag_step<1>(lane, l, Ae, curT0, t0);
            SOFT_FENCE();
        }
        #pragma unroll
        for (int j = 0; j < 4; ++j)            // publish diag (NEG lower kept)
            st_coh4(&s[sidx(b, bi * T + grow, bi * T + gc + 4 * j)],
                    *(const f32x4*)&Ae[grow][gc + 4 * j]);
    } else if (bi + 1 < NB) {
        for (int idx = tid - 64; idx < 256; idx += 192) {
            const int row = idx >> 3, c4 = (idx & 7) * 4;
            *(float4*)&tb[row][c4] =
                *(const float4*)&s[sidx(b, bi * T + row, (bi + 1) * T + c4)];
        }
    }

    // ---- rounds 1..7 ----
    #pragma unroll 1
    for (int D = 1; D < NB; ++D) {
        batch_barrier(bar, b, tid, D);
        const int be = bi + D;
        if (be < NB) {
            if (D == 1) {                      // diag be only final after barrier 1
                f32x4 v = ld_coh4(&s[sidx(b, be * T + trow, be * T + tc4)]);
                BeT[tc4 + 0][trow] = (trow < tc4 + 0) ? v[0] : NEG;
                BeT[tc4 + 1][trow] = (trow < tc4 + 1) ? v[1] : NEG;
                BeT[tc4 + 2][trow] = (trow < tc4 + 2) ? v[2] : NEG;
                BeT[tc4 + 3][trow] = (trow < tc4 + 3) ? v[3] : NEG;
            }
            // GEMM over middle K blocks: A^T resident in LDS, B staged per wave
            const int nw = (D - 1 < 4) ? (D - 1) : 4;
            float ag[4][4];
            #pragma unroll
            for (int i = 0; i < 4; ++i)
                #pragma unroll
                for (int j = 0; j < 4; ++j) ag[i][j] = NEG;
            for (int K = bi + 1 + wid; K < be; K += 4) {
                const float (*AT)[ST] = (const float(*)[ST])(ATb + (K - bi - 1) * SLAB);
                f32x4 b0, b1, b2, b3;
                ld_coh4x4(&s[sidx(b, K * T + grow, be * T + gc)], b0, b1, b2, b3);
                *(f32x4*)&BW[grow][gc + 0]  = b0;
                *(f32x4*)&BW[grow][gc + 4]  = b1;
                *(f32x4*)&BW[grow][gc + 8]  = b2;
                *(f32x4*)&BW[grow][gc + 12] = b3;
                SOFT_FENCE();                  // wave-private BW slab, in-order DS
                #pragma unroll 4
                for (int k = 0; k < T; ++k) {
                    float4 a4 = *(const float4*)&AT[k][r0];
                    float4 b4 = *(const float4*)&BW[k][c0];
                    const float aa[4] = {a4.x, a4.y, a4.z, a4.w};
                    const float bb[4] = {b4.x, b4.y, b4.z, b4.w};
                    #pragma unroll
                    for (int i = 0; i < 4; ++i)
                        #pragma unroll
                        for (int j = 0; j < 4; ++j)
                            ag[i][j] = fmaxf(ag[i][j], aa[i] + bb[j]);
                }
                SOFT_FENCE();
            }
            if (wid < nw) {
                #pragma unroll
                for (int i = 0; i < 4; ++i)
                    *(float4*)&BW[r0 + i][c0] =
                        make_float4(ag[i][0], ag[i][1], ag[i][2], ag[i][3]);
            }
            __syncthreads();
            #pragma unroll
            for (int r = 0; r < 4; ++r) {      // combine wave partials -> pre (=BW0)
                const int row = lr + 8 * r;
                float v = NEG;
                for (int w2 = 0; w2 < nw; ++w2)
                    v = fmaxf(v, BWb[w2 * SLAB + row * ST + lc]);
                pre[row][lc] = v;
            }
            __syncthreads();
            // curT target: persistent A^T slab for D<7 (future GEMM A), scratch last
            float (*curT)[ST] = (D == NB - 1) ? (float(*)[ST])(BWb + 1 * SLAB)
                                              : (float(*)[ST])(ATb + (D - 1) * SLAB);
            #pragma unroll
            for (int r = 0; r < 4; ++r) {
                const int row = lr + 8 * r;
                cur[row][lc]  = NEG;
                curT[row][lc] = NEG;
            }
            __syncthreads();
            if (wid == 0) {                    // wave-synchronous edge pass
                #pragma unroll 1
                for (int l = 0; l < 2 * T - 1; ++l) {
                    const int ad0 = (l < T - 1) ? (T - 1 - l) : (l - (T - 1));
                    if (ad0 >= 16) edge_step<2>(lane, l, D, Ae, BeT, cur, curT, tb, pre);
                    else           edge_step<1>(lane, l, D, Ae, BeT, cur, curT, tb, pre);
                    SOFT_FENCE();
                }
            }
            __syncthreads();
            {                                  // publish (bi,be) for other rows
                f32x4 pv = *(const f32x4*)&cur[trow][tc4];
                st_coh4(&s[sidx(b, bi * T + trow, be * T + tc4)], pv);
            }
            if (be + 1 < NB) {                 // prefetch next round's tb/BeT
                *(float4*)&tb[trow][tc4] =     // phase1-only data: cached path ok
                    *(const float4*)&s[sidx(b, bi * T + trow, (be + 1) * T + tc4)];
                f32x4 v = ld_coh4(&s[sidx(b, (be + 1) * T + trow,
                                          (be + 1) * T + tc4)]);
                BeT[tc4 + 0][trow] = (trow < tc4 + 0) ? v[0] : NEG;
                BeT[tc4 + 1][trow] = (trow < tc4 + 1) ? v[1] : NEG;
                BeT[tc4 + 2][trow] = (trow < tc4 + 2) ? v[2] : NEG;
                BeT[tc4 + 3][trow] = (trow < tc4 + 3) ? v[3] : NEG;
            }
        }
    }

    // Fused finalize: block (b,0) owns row 0, everything needed is in its LDS.
    if (bi == 0 && tid == 0) {
        int len = lens[b];
        len = len < 1 ? 1 : (len > LVAL - 1 ? LVAL - 1 : len);
        const int K = len >> 5, off = len & 31;
        float r;
        if (K == 0)           r = Ae[0][off];
        else if (K == NB - 1) r = cur[0][off];
        else                  r = ATb[(K - 1) * SLAB + off * ST];
        out[b] = r;
    }
}

extern "C" void kernel_launch(void* const* d_in, const int* in_sizes, int n_in,
                              void* d_out, int out_size, void* d_ws, size_t ws_size,
                              hipStream_t stream) {
    const float* scores = (const float*)d_in[0];
    const int*   lens   = (const int*)d_in[1];
    float*       out    = (float*)d_out;
    float*       s      = (float*)d_ws;               // 8 * 256 * 256 f32 = 2 MB
    int*         bar    = (int*)((char*)d_ws + ((size_t)(8) << 16) * sizeof(float));

    phase1<<<dim3(LVAL, 8), 256, 0, stream>>>(scores, s, bar);
    dp_fused<<<64, 256, 0, stream>>>(s, lens, out, bar);
}